// Round 1
// baseline (1949.083 us; speedup 1.0000x reference)
//
#include <hip/hip_runtime.h>

// Wav2Vec BLSTM: 4-layer bi-LSTM (B=32, T=1000, H=32, G=128) + mean-pool + fc.
//
// Pipeline (all fp32):
//   gemm_proj  : xp[dir][b][t][g] = x[b,t,:] . w_ih[dir,g,:] + b_ih + b_hh
//   lstm_rec   : per-(dir,b) wave, 1000 sequential steps, h-broadcast via v_readlane
//   final_fc   : out[b] = mean_t(h_last) . fc_w + fc_b

#define TB 1000
#define NB 32

__device__ __forceinline__ float fsig(float x) {
    float e = __expf(-x);
    return __builtin_amdgcn_rcpf(1.0f + e);
}

__device__ __forceinline__ float f4c(const float4& v, int k) {
    return k == 0 ? v.x : (k == 1 ? v.y : (k == 2 ? v.z : v.w));
}

// ---------------------------------------------------------------------------
// GEMM: A[32000][K] x W[256][K]^T + (bi+bh) -> xp[2][32][1000][128]
// block tile 64 rows x 128 cols, 256 threads, K-chunk 32.
// ---------------------------------------------------------------------------
__global__ __launch_bounds__(256)
void gemm_proj(const float* __restrict__ A, int K,
               const float* __restrict__ W,
               const float* __restrict__ bi,
               const float* __restrict__ bh,
               float* __restrict__ out)
{
    __shared__ float As[64][32];
    __shared__ float Bs[32][132];

    const int tid = threadIdx.x;
    const int m0 = blockIdx.x * 64;
    const int n0 = blockIdx.y * 128;
    const int tx = tid & 31;   // col group (4 cols)
    const int ty = tid >> 5;   // row group (8 rows)

    float acc[8][4];
#pragma unroll
    for (int i = 0; i < 8; ++i)
#pragma unroll
        for (int j = 0; j < 4; ++j) acc[i][j] = 0.0f;

    const int ar0 = tid >> 3;            // rows 0..31
    const int ak0 = (tid & 7) * 4;       // k-offsets 0..28
    const int wr  = tid >> 1;            // W row 0..127
    const int wk  = (tid & 1) * 16;      // k-offset 0 or 16

    for (int k0 = 0; k0 < K; k0 += 32) {
        float4 a0 = *(const float4*)(A + (size_t)(m0 + ar0) * K + k0 + ak0);
        float4 a1 = *(const float4*)(A + (size_t)(m0 + ar0 + 32) * K + k0 + ak0);
        const float* wp = W + (size_t)(n0 + wr) * K + k0 + wk;
        float4 w0 = *(const float4*)(wp + 0);
        float4 w1 = *(const float4*)(wp + 4);
        float4 w2 = *(const float4*)(wp + 8);
        float4 w3 = *(const float4*)(wp + 12);

        __syncthreads();
        *(float4*)&As[ar0][ak0]      = a0;
        *(float4*)&As[ar0 + 32][ak0] = a1;
        {
            float wv[16] = {w0.x, w0.y, w0.z, w0.w,
                            w1.x, w1.y, w1.z, w1.w,
                            w2.x, w2.y, w2.z, w2.w,
                            w3.x, w3.y, w3.z, w3.w};
#pragma unroll
            for (int q = 0; q < 16; ++q) Bs[wk + q][wr] = wv[q];
        }
        __syncthreads();

#pragma unroll
        for (int k4 = 0; k4 < 8; ++k4) {
            float4 av[8];
#pragma unroll
            for (int mi = 0; mi < 8; ++mi)
                av[mi] = *(const float4*)&As[ty * 8 + mi][k4 * 4];
#pragma unroll
            for (int kk = 0; kk < 4; ++kk) {
                float4 bv = *(const float4*)&Bs[k4 * 4 + kk][tx * 4];
#pragma unroll
                for (int mi = 0; mi < 8; ++mi) {
                    float aa = f4c(av[mi], kk);
                    acc[mi][0] = fmaf(aa, bv.x, acc[mi][0]);
                    acc[mi][1] = fmaf(aa, bv.y, acc[mi][1]);
                    acc[mi][2] = fmaf(aa, bv.z, acc[mi][2]);
                    acc[mi][3] = fmaf(aa, bv.w, acc[mi][3]);
                }
            }
        }
    }

    // epilogue: bias + scatter to xp[dir][b][t][g]
    const int dir = n0 >> 7;
    float4 bi4 = *(const float4*)(bi + n0 + tx * 4);
    float4 bh4 = *(const float4*)(bh + n0 + tx * 4);
    float bx = bi4.x + bh4.x, by = bi4.y + bh4.y;
    float bz = bi4.z + bh4.z, bw = bi4.w + bh4.w;
#pragma unroll
    for (int mi = 0; mi < 8; ++mi) {
        int m = m0 + ty * 8 + mi;
        int bb = m / 1000;
        int tt = m - bb * 1000;
        float4 o;
        o.x = acc[mi][0] + bx;
        o.y = acc[mi][1] + by;
        o.z = acc[mi][2] + bz;
        o.w = acc[mi][3] + bw;
        *(float4*)(out + ((size_t)((dir * 32 + bb) * 1000 + tt)) * 128 + tx * 4) = o;
    }
}

// ---------------------------------------------------------------------------
// Recurrence: one wave (64 lanes) per (dir, b). Lane l owns gate rows
// r0 = (l&31) + (l>=32 ? 64 : 0) and r1 = r0+32  (i/f on lanes 0..31,
// g/o on lanes 32..63). h broadcast via v_readlane (no LDS).
// mode 0: write hout[b][t][dir*32+j]; mode 1: accumulate sum_t h -> hsum.
// ---------------------------------------------------------------------------
__global__ __launch_bounds__(64)
void lstm_rec(const float* __restrict__ xp,   // [2][32][1000][128]
              const float* __restrict__ whh,  // [2][128][32]
              float* __restrict__ hout,       // [32][1000][64]
              float* __restrict__ hsum,       // [32][64]
              int mode)
{
    const int blk  = blockIdx.x;   // dir*32 + b
    const int dir  = blk >> 5;
    const int b    = blk & 31;
    const int lane = threadIdx.x & 63;
    const int j    = lane & 31;
    const int up   = lane >> 5;
    const int r0   = j + up * 64;
    const int r1   = r0 + 32;

    // recurrent weights: 64 floats per lane, kept in VGPRs
    float w0[32], w1[32];
    {
        const float* wp0 = whh + (size_t)(dir * 128 + r0) * 32;
        const float* wp1 = whh + (size_t)(dir * 128 + r1) * 32;
#pragma unroll
        for (int q = 0; q < 8; ++q) {
            float4 v = *(const float4*)(wp0 + q * 4);
            w0[q * 4 + 0] = v.x; w0[q * 4 + 1] = v.y;
            w0[q * 4 + 2] = v.z; w0[q * 4 + 3] = v.w;
            float4 u = *(const float4*)(wp1 + q * 4);
            w1[q * 4 + 0] = u.x; w1[q * 4 + 1] = u.y;
            w1[q * 4 + 2] = u.z; w1[q * 4 + 3] = u.w;
        }
    }

    const float* xpb = xp + (size_t)(dir * 32 + b) * TB * 128;
    const int t0 = dir ? (TB - 1) : 0;
    const int dt = dir ? -1 : 1;
    const float* pa = xpb + r0;
    const float* pb = xpb + r1;

    // 2-deep register prefetch of xp
    float a_c = pa[t0 * 128];
    float b_c = pb[t0 * 128];
    float a_n = pa[(t0 + dt) * 128];
    float b_n = pb[(t0 + dt) * 128];

    float c = 0.0f, h = 0.0f, hacc = 0.0f;
    float* hop = hout + (size_t)b * TB * 64 + dir * 32 + j;

    for (int i = 0; i < TB; ++i) {
        const int t = t0 + i * dt;

        float a_f = 0.0f, b_f = 0.0f;
        if (i + 2 < TB) {
            const int tf = t + 2 * dt;
            a_f = pa[tf * 128];
            b_f = pb[tf * 128];
        }

        // gates: acc = xp + h . Whh^T   (h broadcast via readlane -> SGPRs)
        float acc00 = a_c, acc01 = 0.0f, acc02 = 0.0f, acc03 = 0.0f;
        float acc10 = b_c, acc11 = 0.0f, acc12 = 0.0f, acc13 = 0.0f;
#pragma unroll
        for (int q = 0; q < 8; ++q) {
            float hk0 = __int_as_float(__builtin_amdgcn_readlane(__float_as_int(h), 4 * q + 0));
            float hk1 = __int_as_float(__builtin_amdgcn_readlane(__float_as_int(h), 4 * q + 1));
            float hk2 = __int_as_float(__builtin_amdgcn_readlane(__float_as_int(h), 4 * q + 2));
            float hk3 = __int_as_float(__builtin_amdgcn_readlane(__float_as_int(h), 4 * q + 3));
            acc00 = fmaf(hk0, w0[4 * q + 0], acc00);
            acc01 = fmaf(hk1, w0[4 * q + 1], acc01);
            acc02 = fmaf(hk2, w0[4 * q + 2], acc02);
            acc03 = fmaf(hk3, w0[4 * q + 3], acc03);
            acc10 = fmaf(hk0, w1[4 * q + 0], acc10);
            acc11 = fmaf(hk1, w1[4 * q + 1], acc11);
            acc12 = fmaf(hk2, w1[4 * q + 2], acc12);
            acc13 = fmaf(hk3, w1[4 * q + 3], acc13);
        }
        float a0 = (acc00 + acc01) + (acc02 + acc03);
        float a1 = (acc10 + acc11) + (acc12 + acc13);

        // lanes<32: a0=i (sigmoid), a1=f (sigmoid)
        // lanes>=32: a0=g (tanh = 2*sig(2x)-1), a1=o (sigmoid)
        float x0 = up ? 2.0f * a0 : a0;
        float s0 = fsig(x0);
        float v0 = up ? 2.0f * s0 - 1.0f : s0;
        float v1 = fsig(a1);

        float o0 = __shfl_xor(v0, 32, 64);
        float o1 = __shfl_xor(v1, 32, 64);

        float sig_i = up ? o0 : v0;
        float sig_f = up ? o1 : v1;
        float tg    = up ? v0 : o0;
        float sig_o = up ? v1 : o1;

        c = fmaf(sig_f, c, sig_i * tg);
        float s2 = fsig(2.0f * c);
        float tc = 2.0f * s2 - 1.0f;
        h = sig_o * tc;

        if (mode == 0) {
            if (!up) hop[(size_t)t * 64] = h;
        } else {
            hacc += h;
        }

        a_c = a_n; b_c = b_n; a_n = a_f; b_n = b_f;
    }

    if (mode != 0 && !up) hsum[b * 64 + dir * 32 + j] = hacc;
}

// ---------------------------------------------------------------------------
// out[b] = (hsum[b,:]/T) . fc_w + fc_b
// ---------------------------------------------------------------------------
__global__ __launch_bounds__(64)
void final_fc(const float* __restrict__ hsum,
              const float* __restrict__ fcw,
              const float* __restrict__ fcb,
              float* __restrict__ out)
{
    int b = blockIdx.x;
    int l = threadIdx.x;
    float v = hsum[b * 64 + l] * (1.0f / (float)TB) * fcw[l];
#pragma unroll
    for (int off = 32; off > 0; off >>= 1)
        v += __shfl_down(v, off, 64);
    if (l == 0) out[b] = v + fcb[0];
}

// ---------------------------------------------------------------------------
extern "C" void kernel_launch(void* const* d_in, const int* in_sizes, int n_in,
                              void* d_out, int out_size, void* d_ws, size_t ws_size,
                              hipStream_t stream)
{
    const float* x    = (const float*)d_in[0];
    const float* wih0 = (const float*)d_in[1];
    const float* whh0 = (const float*)d_in[2];
    const float* bih0 = (const float*)d_in[3];
    const float* bhh0 = (const float*)d_in[4];
    const float* wih  = (const float*)d_in[5];
    const float* whh  = (const float*)d_in[6];
    const float* bih  = (const float*)d_in[7];
    const float* bhh  = (const float*)d_in[8];
    const float* fcw  = (const float*)d_in[9];
    const float* fcb  = (const float*)d_in[10];
    float* out = (float*)d_out;

    float* ws = (float*)d_ws;
    float* xp = ws;                         // 2*32*1000*128 = 8,192,000 floats
    float* hb = ws + 8192000;               // 32*1000*64    = 2,048,000 floats
    float* hs = ws + 8192000 + 2048000;     // 32*64         = 2,048 floats

    dim3 gb(500, 2);

    // layer 0
    gemm_proj<<<gb, 256, 0, stream>>>(x, 1024, wih0, bih0, bhh0, xp);
    lstm_rec<<<64, 64, 0, stream>>>(xp, whh0, hb, hs, 0);

    // layers 1..3
    for (int l = 1; l < 4; ++l) {
        const float* wl  = wih + (size_t)(l - 1) * 2 * 128 * 64;
        const float* whl = whh + (size_t)(l - 1) * 2 * 128 * 32;
        const float* b1  = bih + (size_t)(l - 1) * 256;
        const float* b2  = bhh + (size_t)(l - 1) * 256;
        gemm_proj<<<gb, 256, 0, stream>>>(hb, 64, wl, b1, b2, xp);
        lstm_rec<<<64, 64, 0, stream>>>(xp, whl, hb, hs, (l == 3) ? 1 : 0);
    }

    final_fc<<<32, 64, 0, stream>>>(hs, fcw, fcb, out);
}

// Round 2
// 1343.770 us; speedup vs baseline: 1.4505x; 1.4505x over previous
//
#include <hip/hip_runtime.h>

// Wav2Vec BLSTM: 4-layer bi-LSTM (B=32, T=1000, H=32, G=128) + mean-pool + fc.
//
// Round 2:
//  - xp stored transposed [chain][gate_row][t] (bwd chains time-reversed at
//    GEMM epilogue) -> contiguous float4 gate streams in the recurrence,
//    unconditional clamped prefetch 8-12 steps ahead (no per-step vmcnt drain).
//  - __shfl_xor(32) replaced by v_permlane32_swap_b32 (VALU) with a per-lane
//    convention-independent word pick.
//  - tanh/sigmoid prescale folded into per-lane constants.

#define TB 1000

typedef int v2i __attribute__((ext_vector_type(2)));

// returns v[lane ^ 32]; pickx precomputed per-lane (convention-independent)
__device__ __forceinline__ float lane_xor32(float v, bool pickx) {
    v2i r = __builtin_amdgcn_permlane32_swap(__float_as_int(v), __float_as_int(v),
                                             false, false);
    return __int_as_float(pickx ? r[0] : r[1]);
}

// ---------------------------------------------------------------------------
// GEMM: A[32000][K] x W[256][K]^T + (bi+bh) -> xpT[2*32][128][1000]
// (dir=1 stored time-reversed). Tile 64 m x 128 n, 256 threads, K-chunk 32.
// Thread owns 8 n x 4 consecutive m -> float4 stores along t.
// ---------------------------------------------------------------------------
__global__ __launch_bounds__(256)
void gemm_proj(const float* __restrict__ A, int K,
               const float* __restrict__ W,
               const float* __restrict__ bi,
               const float* __restrict__ bh,
               float* __restrict__ xpT)
{
    __shared__ __align__(16) float As[32][68];    // [k][m]
    __shared__ __align__(16) float Bs[32][132];   // [k][n]

    const int tid = threadIdx.x;
    const int m0 = blockIdx.x * 64;
    const int n0 = blockIdx.y * 128;
    const int tx = tid & 15;     // m-quad:  m = m0 + tx*4 + mj
    const int ty = tid >> 4;     // n-octet: n = n0 + ty*8 + ni

    float acc[8][4];
#pragma unroll
    for (int i = 0; i < 8; ++i)
#pragma unroll
        for (int jj = 0; jj < 4; ++jj) acc[i][jj] = 0.0f;

    const int ar = tid >> 3;           // 0..31
    const int ak = (tid & 7) * 4;      // 0..28
    const int wr = tid >> 1;           // 0..127
    const int wk = (tid & 1) * 16;     // 0 / 16

    for (int k0 = 0; k0 < K; k0 += 32) {
        float4 a0 = *(const float4*)(A + (size_t)(m0 + ar) * K + k0 + ak);
        float4 a1 = *(const float4*)(A + (size_t)(m0 + ar + 32) * K + k0 + ak);
        const float* wp = W + (size_t)(n0 + wr) * K + k0 + wk;
        float4 w0 = *(const float4*)(wp + 0);
        float4 w1 = *(const float4*)(wp + 4);
        float4 w2 = *(const float4*)(wp + 8);
        float4 w3 = *(const float4*)(wp + 12);

        __syncthreads();
        As[ak + 0][ar] = a0.x; As[ak + 1][ar] = a0.y;
        As[ak + 2][ar] = a0.z; As[ak + 3][ar] = a0.w;
        As[ak + 0][ar + 32] = a1.x; As[ak + 1][ar + 32] = a1.y;
        As[ak + 2][ar + 32] = a1.z; As[ak + 3][ar + 32] = a1.w;
        {
            float wv[16] = {w0.x, w0.y, w0.z, w0.w,
                            w1.x, w1.y, w1.z, w1.w,
                            w2.x, w2.y, w2.z, w2.w,
                            w3.x, w3.y, w3.z, w3.w};
#pragma unroll
            for (int q = 0; q < 16; ++q) Bs[wk + q][wr] = wv[q];
        }
        __syncthreads();

#pragma unroll
        for (int kk = 0; kk < 32; ++kk) {
            float4 av = *(const float4*)&As[kk][tx * 4];
            float4 b0 = *(const float4*)&Bs[kk][ty * 8];
            float4 b1 = *(const float4*)&Bs[kk][ty * 8 + 4];
            float bn[8] = {b0.x, b0.y, b0.z, b0.w, b1.x, b1.y, b1.z, b1.w};
#pragma unroll
            for (int ni = 0; ni < 8; ++ni) {
                acc[ni][0] = fmaf(av.x, bn[ni], acc[ni][0]);
                acc[ni][1] = fmaf(av.y, bn[ni], acc[ni][1]);
                acc[ni][2] = fmaf(av.z, bn[ni], acc[ni][2]);
                acc[ni][3] = fmaf(av.w, bn[ni], acc[ni][3]);
            }
        }
    }

    // epilogue: bias + transposed (and for dir=1 time-reversed) store
    const int dir = n0 >> 7;
    const int mbase = m0 + tx * 4;
    const int bidx = mbase / 1000;        // 1000 % 4 == 0: quad never crosses b
    const int ttq = mbase - bidx * 1000;
#pragma unroll
    for (int ni = 0; ni < 8; ++ni) {
        const int n = n0 + ty * 8 + ni;
        const float bias = bi[n] + bh[n];
        float* row = xpT + ((size_t)((dir * 32 + bidx) * 128) + (n & 127)) * TB;
        if (dir == 0) {
            float4 o = {acc[ni][0] + bias, acc[ni][1] + bias,
                        acc[ni][2] + bias, acc[ni][3] + bias};
            *(float4*)(row + ttq) = o;
        } else {
            float4 o = {acc[ni][3] + bias, acc[ni][2] + bias,
                        acc[ni][1] + bias, acc[ni][0] + bias};
            *(float4*)(row + (TB - 4 - ttq)) = o;
        }
    }
}

// ---------------------------------------------------------------------------
// Recurrence: one wave per (dir,b). Lane l owns gate rows r0=(l&31)+(l>=32?64:0)
// and r1=r0+32. h broadcast via readlane; half-exchange via permlane32_swap.
// xpT streams are contiguous in t (bwd already reversed) -> float4 prefetch.
// ---------------------------------------------------------------------------
template<int MODE>
__global__ __launch_bounds__(64)
void lstm_rec(const float* __restrict__ xpT,  // [64][128][1000]
              const float* __restrict__ whh,  // [2][128][32]
              float* __restrict__ hout,       // [32][1000][64]
              float* __restrict__ hsum)       // [32][64]
{
    const int blk  = blockIdx.x;   // dir*32 + b
    const int dir  = blk >> 5;
    const int b    = blk & 31;
    const int lane = threadIdx.x & 63;
    const int j    = lane & 31;
    const int up   = lane >> 5;
    const int r0   = j + up * 64;
    const int r1   = r0 + 32;

    // detect permlane32_swap half-direction once (convention-independent)
    v2i det = __builtin_amdgcn_permlane32_swap(lane, lane, false, false);
    const bool pickx = (det[0] == (lane ^ 32));

    // recurrent weights in VGPRs
    float w0[32], w1[32];
    {
        const float* wp0 = whh + (size_t)(dir * 128 + r0) * 32;
        const float* wp1 = whh + (size_t)(dir * 128 + r1) * 32;
#pragma unroll
        for (int q = 0; q < 8; ++q) {
            float4 v = *(const float4*)(wp0 + q * 4);
            w0[q * 4 + 0] = v.x; w0[q * 4 + 1] = v.y;
            w0[q * 4 + 2] = v.z; w0[q * 4 + 3] = v.w;
            float4 u = *(const float4*)(wp1 + q * 4);
            w1[q * 4 + 0] = u.x; w1[q * 4 + 1] = u.y;
            w1[q * 4 + 2] = u.z; w1[q * 4 + 3] = u.w;
        }
    }

    const float* pa = xpT + ((size_t)blk * 128 + r0) * TB;
    const float* pb = xpT + ((size_t)blk * 128 + r1) * TB;

    float4 A0 = *(const float4*)(pa + 0);
    float4 B0 = *(const float4*)(pb + 0);
    float4 A1 = *(const float4*)(pa + 4);
    float4 B1 = *(const float4*)(pb + 4);

    // per-lane nonlinearity constants: lanes<32 sigmoid, lanes>=32 tanh map
    const float kS0 = up ? -2.0f : -1.0f;
    const float mA  = up ?  2.0f : 1.0f;
    const float mB  = up ? -1.0f : 0.0f;

    float c = 0.0f, h = 0.0f, hacc = 0.0f;
    float* hq = hout + ((size_t)b * TB + (dir ? TB - 1 : 0)) * 64 + dir * 32 + j;
    const int hstep = dir ? -64 : 64;

#define LSTM_STEP(GA, GB) do {                                                  \
        float q00 = (GA), q01 = 0.f, q02 = 0.f, q03 = 0.f;                      \
        float q10 = (GB), q11 = 0.f, q12 = 0.f, q13 = 0.f;                      \
        _Pragma("unroll")                                                       \
        for (int q = 0; q < 8; ++q) {                                           \
            float hk0 = __int_as_float(__builtin_amdgcn_readlane(__float_as_int(h), 4*q+0)); \
            float hk1 = __int_as_float(__builtin_amdgcn_readlane(__float_as_int(h), 4*q+1)); \
            float hk2 = __int_as_float(__builtin_amdgcn_readlane(__float_as_int(h), 4*q+2)); \
            float hk3 = __int_as_float(__builtin_amdgcn_readlane(__float_as_int(h), 4*q+3)); \
            q00 = fmaf(hk0, w0[4*q+0], q00);                                    \
            q01 = fmaf(hk1, w0[4*q+1], q01);                                    \
            q02 = fmaf(hk2, w0[4*q+2], q02);                                    \
            q03 = fmaf(hk3, w0[4*q+3], q03);                                    \
            q10 = fmaf(hk0, w1[4*q+0], q10);                                    \
            q11 = fmaf(hk1, w1[4*q+1], q11);                                    \
            q12 = fmaf(hk2, w1[4*q+2], q12);                                    \
            q13 = fmaf(hk3, w1[4*q+3], q13);                                    \
        }                                                                       \
        float g0 = (q00 + q01) + (q02 + q03);                                   \
        float g1 = (q10 + q11) + (q12 + q13);                                   \
        float e0 = __expf(g0 * kS0);                                            \
        float s0 = __builtin_amdgcn_rcpf(1.0f + e0);                            \
        float v0 = fmaf(mA, s0, mB);   /* lo: sig(i); hi: tanh(g) */            \
        float e1 = __expf(-g1);                                                 \
        float v1 = __builtin_amdgcn_rcpf(1.0f + e1); /* lo: sig(f); hi: sig(o) */ \
        float o0 = lane_xor32(v0, pickx);                                       \
        float o1 = lane_xor32(v1, pickx);                                       \
        float si = up ? o0 : v0;                                                \
        float sf = up ? o1 : v1;                                                \
        float tg = up ? v0 : o0;                                                \
        float so = up ? v1 : o1;                                                \
        c = fmaf(sf, c, si * tg);                                               \
        float ec = __expf(-2.0f * c);                                           \
        float tc = fmaf(2.0f, __builtin_amdgcn_rcpf(1.0f + ec), -1.0f);         \
        h = so * tc;                                                            \
        if (MODE == 0) { if (!up) *hq = h; } else { hacc += h; }                \
        hq += hstep;                                                            \
    } while (0)

    for (int it = 0; it < 125; ++it) {
        const int base = it * 8;
        const int offn0 = min(base + 8,  TB - 4);   // clamped, unconditional
        const int offn1 = min(base + 12, TB - 4);
        float4 NA0 = *(const float4*)(pa + offn0);
        float4 NB0 = *(const float4*)(pb + offn0);
        float4 NA1 = *(const float4*)(pa + offn1);
        float4 NB1 = *(const float4*)(pb + offn1);

        LSTM_STEP(A0.x, B0.x);
        LSTM_STEP(A0.y, B0.y);
        LSTM_STEP(A0.z, B0.z);
        LSTM_STEP(A0.w, B0.w);
        LSTM_STEP(A1.x, B1.x);
        LSTM_STEP(A1.y, B1.y);
        LSTM_STEP(A1.z, B1.z);
        LSTM_STEP(A1.w, B1.w);

        A0 = NA0; B0 = NB0; A1 = NA1; B1 = NB1;
    }
#undef LSTM_STEP

    if (MODE == 1 && !up) hsum[b * 64 + dir * 32 + j] = hacc;
}

// ---------------------------------------------------------------------------
// out[b] = (hsum[b,:]/T) . fc_w + fc_b
// ---------------------------------------------------------------------------
__global__ __launch_bounds__(64)
void final_fc(const float* __restrict__ hsum,
              const float* __restrict__ fcw,
              const float* __restrict__ fcb,
              float* __restrict__ out)
{
    int b = blockIdx.x;
    int l = threadIdx.x;
    float v = hsum[b * 64 + l] * (1.0f / (float)TB) * fcw[l];
#pragma unroll
    for (int off = 32; off > 0; off >>= 1)
        v += __shfl_down(v, off, 64);
    if (l == 0) out[b] = v + fcb[0];
}

// ---------------------------------------------------------------------------
extern "C" void kernel_launch(void* const* d_in, const int* in_sizes, int n_in,
                              void* d_out, int out_size, void* d_ws, size_t ws_size,
                              hipStream_t stream)
{
    const float* x    = (const float*)d_in[0];
    const float* wih0 = (const float*)d_in[1];
    const float* whh0 = (const float*)d_in[2];
    const float* bih0 = (const float*)d_in[3];
    const float* bhh0 = (const float*)d_in[4];
    const float* wih  = (const float*)d_in[5];
    const float* whh  = (const float*)d_in[6];
    const float* bih  = (const float*)d_in[7];
    const float* bhh  = (const float*)d_in[8];
    const float* fcw  = (const float*)d_in[9];
    const float* fcb  = (const float*)d_in[10];
    float* out = (float*)d_out;

    float* ws = (float*)d_ws;
    float* xp = ws;                         // 64*128*1000 = 8,192,000 floats
    float* hb = ws + 8192000;               // 32*1000*64  = 2,048,000 floats
    float* hs = ws + 8192000 + 2048000;     // 32*64

    dim3 gb(500, 2);

    // layer 0
    gemm_proj<<<gb, 256, 0, stream>>>(x, 1024, wih0, bih0, bhh0, xp);
    lstm_rec<0><<<64, 64, 0, stream>>>(xp, whh0, hb, hs);

    // layers 1..3
    for (int l = 1; l < 4; ++l) {
        const float* wl  = wih + (size_t)(l - 1) * 2 * 128 * 64;
        const float* whl = whh + (size_t)(l - 1) * 2 * 128 * 32;
        const float* b1  = bih + (size_t)(l - 1) * 256;
        const float* b2  = bhh + (size_t)(l - 1) * 256;
        gemm_proj<<<gb, 256, 0, stream>>>(hb, 64, wl, b1, b2, xp);
        if (l == 3) lstm_rec<1><<<64, 64, 0, stream>>>(xp, whl, hb, hs);
        else        lstm_rec<0><<<64, 64, 0, stream>>>(xp, whl, hb, hs);
    }

    final_fc<<<32, 64, 0, stream>>>(hs, fcw, fcb, out);
}